// Round 10
// baseline (3995.154 us; speedup 1.0000x reference)
//
#include <hip/hip_runtime.h>

// ---------------------------------------------------------------------------
// LoRA QKV fused projection on MI355X (gfx950)
// Weff-folding (LoRA into weights) + ONE bf16 MFMA GEMM (16x16x32 frags,
// R4's verified staging swizzle + conflict-free read path).
// R10: occupancy axis — LDS ring 4 -> 2 slots (128 -> 64 KB) => 2 blocks/CU.
//   Per slice: read h0+B frags; MFMA h0; read h1; lgkmcnt(0)+barrier (slot-s
//   reads drained); stage slice s+2 into the just-freed slot; MFMA h1;
//   vmcnt(4); barrier.  2 barriers/slice (was 4), counted vmcnt preserved.
//   Rationale: R4's missing ~50% is barrier/latency gap with 1 resident
//   block; a second block's MFMA fills it (m97/m114 mechanism).
// ---------------------------------------------------------------------------

#define GLOBAL_AS __attribute__((address_space(1)))
#define LDS_AS    __attribute__((address_space(3)))

typedef __attribute__((ext_vector_type(8))) short  short8;   // 8 bf16 (MFMA A/B frag)
typedef __attribute__((ext_vector_type(4))) float  floatx4;  // MFMA C/D frag

constexpr int Mdim = 8192;   // B*S
constexpr int Kdim = 4096;   // H
constexpr int NQ   = 4096;
constexpr int NKV  = 1024;
constexpr int NTOT = NQ + 2 * NKV;  // 6144
constexpr float LORA_SCALE = 2.0f;

constexpr int BM = 256, BN = 256;
constexpr int TILES_M = Mdim / BM;      // 32
constexpr int TILES_N = NTOT / BN;      // 24
constexpr int NWG = TILES_M * TILES_N;  // 768 (%8==0 -> bijective XCD swizzle)
constexpr int NSLICE = Kdim / 32;       // 128 K-slices of 32

constexpr int WEFF_BLOCKS = (NTOT / 64) * (Kdim / 512);  // 768
constexpr int CVT_BLOCKS  = 2048;
constexpr int AT_STRIDE   = 516;

__device__ __forceinline__ unsigned short f2bf(float f) {
    union { float f; unsigned int u; } a; a.f = f;
    unsigned int r = a.u + 0x7FFFu + ((a.u >> 16) & 1u);
    return (unsigned short)(r >> 16);
}

// ---------------------------------------------------------------------------
// Fused prep (identical to R4 — linear row-major outputs):
//   blocks [0, WEFF_BLOCKS): Weff[n,h] = W[n,h] + 2*sum_r A[h,r]B[r,n] -> bf16
//   blocks [WEFF_BLOCKS, +CVT_BLOCKS): X fp32 -> bf16.
// ---------------------------------------------------------------------------
__global__ __launch_bounds__(256)
void prep_kernel(const float4* __restrict__ x4, unsigned short* __restrict__ Xbf,
                 const float* __restrict__ Wq, const float* __restrict__ Wk,
                 const float* __restrict__ Wv,
                 const float* __restrict__ Aq, const float* __restrict__ Bq,
                 const float* __restrict__ Ak, const float* __restrict__ Bk,
                 const float* __restrict__ Av, const float* __restrict__ Bv,
                 unsigned short* __restrict__ Wf) {
    __shared__ float AsT[16 * AT_STRIDE];   // ~33 KB: A^T chunk, [r][h_local]
    __shared__ float Bsc[64 * 16];          // 4 KB: 2*B[r, n0+..] as [n][r]

    const int tid = threadIdx.x;

    if (blockIdx.x >= WEFF_BLOCKS) {
        int i = (blockIdx.x - WEFF_BLOCKS) * 256 + tid;
        const int stride = CVT_BLOCKS * 256;
        const int n4 = Mdim * Kdim / 4;
        ushort4* out = (ushort4*)Xbf;
        for (; i < n4; i += stride) {
            float4 v = x4[i];
            ushort4 u;
            u.x = f2bf(v.x); u.y = f2bf(v.y); u.z = f2bf(v.z); u.w = f2bf(v.w);
            out[i] = u;
        }
        return;
    }

    const int n0 = (blockIdx.x >> 3) * 64;      // 64-row group (never straddles seg)
    const int h0 = (blockIdx.x & 7) * 512;

    const float* W; const float* A; const float* Bm; int O; int nn0;
    if (n0 < NQ)            { W = Wq; A = Aq; Bm = Bq; O = NQ;  nn0 = n0; }
    else if (n0 < NQ + NKV) { W = Wk; A = Ak; Bm = Bk; O = NKV; nn0 = n0 - NQ; }
    else                    { W = Wv; A = Av; Bm = Bv; O = NKV; nn0 = n0 - NQ - NKV; }

    {
        const float4* Af4 = (const float4*)(A) + h0 * 4;
        #pragma unroll
        for (int i = 0; i < 8; ++i) {
            const int f = i * 256 + tid;
            const float4 v = Af4[f];
            const int hl = f >> 2;
            const int r0 = (f & 3) * 4;
            AsT[(r0 + 0) * AT_STRIDE + hl] = v.x;
            AsT[(r0 + 1) * AT_STRIDE + hl] = v.y;
            AsT[(r0 + 2) * AT_STRIDE + hl] = v.z;
            AsT[(r0 + 3) * AT_STRIDE + hl] = v.w;
        }
    }
    {
        const int nl = tid & 63;
        const int rq = tid >> 6;        // 0..3
        #pragma unroll
        for (int j = 0; j < 4; ++j) {
            const int r = rq * 4 + j;
            Bsc[nl * 16 + r] = Bm[r * O + nn0 + nl] * LORA_SCALE;
        }
    }
    __syncthreads();

    const int wv_ = tid >> 6;
    const int lane = tid & 63;

    #pragma unroll
    for (int pass = 0; pass < 2; ++pass) {
        const int hl = pass * 256 + lane * 4;
        float4 areg[16];
        #pragma unroll
        for (int r = 0; r < 16; ++r)
            areg[r] = *(const float4*)(&AsT[r * AT_STRIDE + hl]);

        for (int i = 0; i < 16; ++i) {
            const int nl = wv_ * 16 + i;
            const float4 w4 = *(const float4*)(W + (size_t)(nn0 + nl) * Kdim + h0 + hl);
            const float4* b4 = (const float4*)(&Bsc[nl * 16]);
            float4 d = {0.f, 0.f, 0.f, 0.f};
            #pragma unroll
            for (int q = 0; q < 4; ++q) {
                const float4 b = b4[q];
                d.x += areg[q*4+0].x * b.x + areg[q*4+1].x * b.y + areg[q*4+2].x * b.z + areg[q*4+3].x * b.w;
                d.y += areg[q*4+0].y * b.x + areg[q*4+1].y * b.y + areg[q*4+2].y * b.z + areg[q*4+3].y * b.w;
                d.z += areg[q*4+0].z * b.x + areg[q*4+1].z * b.y + areg[q*4+2].z * b.z + areg[q*4+3].z * b.w;
                d.w += areg[q*4+0].w * b.x + areg[q*4+1].w * b.y + areg[q*4+2].w * b.z + areg[q*4+3].w * b.w;
            }
            ushort4 u;
            u.x = f2bf(w4.x + d.x); u.y = f2bf(w4.y + d.y);
            u.z = f2bf(w4.z + d.z); u.w = f2bf(w4.w + d.w);
            *(ushort4*)(Wf + (size_t)(n0 + nl) * Kdim + h0 + hl) = u;
        }
    }
}

// ---------------------------------------------------------------------------
// GEMM: out[M, NTOT] = Xbf[M,K] . Wf[NTOT,K]^T + bias, scattered to q/k/v.
//
// LDS: A/B rings of TWO K-slices (slice = 2 halves x 128 rows x 32 k, 16 KB)
// -> 64 KB total -> 2 blocks/CU. Staging/read paths identical to R4
// (16-B-chunk swizzle; pre-permuted per-lane source k; coalesced 64-B
// segments). Slice s lives in slot s&1.
//
// Per-slice step (slot = s&1):
//   ds_read A-h0 (4) + B (4); MFMA h0 (16, setprio);
//   ds_read A-h1 (4); lgkmcnt(0); s_barrier       <- all slot-s reads done
//   STAGE slice s+2 -> same slot (freed);          (4 global_load_lds)
//   MFMA h1 (16, setprio); vmcnt(4); s_barrier    <- slice s+1 landed
// vmcnt ledger: outstanding at step end = {s+1:4, s+2:4} = 8 -> vmcnt(4)
// retires s+1 (issued one full slice earlier). Tail: s=126 no stage,
// vmcnt(0) lands 127; s=127 bare.
// ---------------------------------------------------------------------------
__global__ __launch_bounds__(512, 4)
void gemm_qkv_kernel(const unsigned short* __restrict__ X,
                     const unsigned short* __restrict__ Wf,
                     const float* __restrict__ bq, const float* __restrict__ bk,
                     const float* __restrict__ bv,
                     float* __restrict__ out) {
    __shared__ __align__(16) unsigned short Abuf[2][8192];  // 32 KB
    __shared__ __align__(16) unsigned short Bbuf[2][8192];  // 32 KB

    const int tid  = threadIdx.x;
    const int lane = tid & 63;
    const int w    = tid >> 6;
    const int wr   = w >> 2;        // 0..1  (M half)
    const int wc   = w & 3;         // 0..3  (N quarter)

    int bid = blockIdx.x;
    bid = (bid & 7) * (NWG / 8) + (bid >> 3);   // XCD-aware, bijective (768%8==0)
    const int row0 = (bid / TILES_N) * BM;
    const int col0 = (bid % TILES_N) * BN;

    // ds_read addressing (16-B chunk swizzle, verified conflict-free):
    // lane reads row (lane&15), k-chunk kh=lane>>4 from phys chunk kh^((row>>1)&3)
    const int swz    = (((lane >> 4) ^ ((lane >> 1) & 3)) << 4);    // bytes
    const int aByte0 = (wr * 128 + (lane & 15)) * 64 + swz;
    const int bByte0 = (wc * 64  + (lane & 15)) * 64 + swz;

    // staging source addressing (pre-permuted k so linear LDS dest ends swizzled)
    const int srow = (w << 4) + (lane >> 2);                         // 0..127
    const int kswz = (((lane & 3) ^ ((lane >> 3) & 3)) << 3);        // elements
    const unsigned short* pA0 = X  + (size_t)(row0 + srow) * Kdim + kswz;
    const unsigned short* pA1 = pA0 + (size_t)128 * Kdim;
    const unsigned short* pB0 = Wf + (size_t)(col0 + srow) * Kdim + kswz;
    const unsigned short* pB1 = pB0 + (size_t)128 * Kdim;

    floatx4 acc[8][4];
    #pragma unroll
    for (int i = 0; i < 8; ++i)
        #pragma unroll
        for (int j = 0; j < 4; ++j)
            acc[i][j] = (floatx4){0.f, 0.f, 0.f, 0.f};

#define STAGE(MATA, SS, SLOT)                                                    \
    { const int ss_ = (SS);                                                      \
      if (MATA) {                                                                \
        __builtin_amdgcn_global_load_lds((const GLOBAL_AS void*)(pA0 + ss_ * 32),\
            (LDS_AS void*)(&Abuf[SLOT][w * 512]),        16, 0, 0);              \
        __builtin_amdgcn_global_load_lds((const GLOBAL_AS void*)(pA1 + ss_ * 32),\
            (LDS_AS void*)(&Abuf[SLOT][4096 + w * 512]), 16, 0, 0);              \
      } else {                                                                   \
        __builtin_amdgcn_global_load_lds((const GLOBAL_AS void*)(pB0 + ss_ * 32),\
            (LDS_AS void*)(&Bbuf[SLOT][w * 512]),        16, 0, 0);              \
        __builtin_amdgcn_global_load_lds((const GLOBAL_AS void*)(pB1 + ss_ * 32),\
            (LDS_AS void*)(&Bbuf[SLOT][4096 + w * 512]), 16, 0, 0);              \
      } }

// WM: 0 none, 1 vmcnt(4), 2 vmcnt(0), 3 final (no vmcnt, no end barrier)
#define SLICE_STEP(SLOT, DOSTAGE, SS, WM)                                        \
    { const char* ab_ = (const char*)Abuf + (SLOT) * 16384;                      \
      const char* bb_ = (const char*)Bbuf + (SLOT) * 16384;                      \
      short8 af0[4], af1[4], bfr[4];                                             \
      _Pragma("unroll")                                                          \
      for (int mf = 0; mf < 4; ++mf)                                             \
        af0[mf] = *(const short8*)(ab_ + aByte0 + mf * 1024);                    \
      _Pragma("unroll")                                                          \
      for (int nf = 0; nf < 4; ++nf)                                             \
        bfr[nf] = *(const short8*)(bb_ + bByte0 + nf * 1024);                    \
      __builtin_amdgcn_s_setprio(1);                                             \
      _Pragma("unroll")                                                          \
      for (int mf = 0; mf < 4; ++mf)                                             \
        _Pragma("unroll")                                                        \
        for (int nf = 0; nf < 4; ++nf)                                           \
          acc[mf][nf] = __builtin_amdgcn_mfma_f32_16x16x32_bf16(                 \
              af0[mf], bfr[nf], acc[mf][nf], 0, 0, 0);                           \
      __builtin_amdgcn_s_setprio(0);                                             \
      _Pragma("unroll")                                                          \
      for (int mf = 0; mf < 4; ++mf)                                             \
        af1[mf] = *(const short8*)(ab_ + aByte0 + (4 + mf) * 1024);              \
      asm volatile("s_waitcnt lgkmcnt(0)" ::: "memory");                         \
      __builtin_amdgcn_s_barrier();                                              \
      if (DOSTAGE) { STAGE(1, SS, SLOT); STAGE(0, SS, SLOT); }                   \
      __builtin_amdgcn_s_setprio(1);                                             \
      _Pragma("unroll")                                                          \
      for (int mf = 0; mf < 4; ++mf)                                             \
        _Pragma("unroll")                                                        \
        for (int nf = 0; nf < 4; ++nf)                                           \
          acc[4 + mf][nf] = __builtin_amdgcn_mfma_f32_16x16x32_bf16(             \
              af1[mf], bfr[nf], acc[4 + mf][nf], 0, 0, 0);                       \
      __builtin_amdgcn_s_setprio(0);                                             \
      if ((WM) == 1) asm volatile("s_waitcnt vmcnt(4)" ::: "memory");            \
      if ((WM) == 2) asm volatile("s_waitcnt vmcnt(0)" ::: "memory");            \
      if ((WM) != 3) __builtin_amdgcn_s_barrier(); }

    // ---- prologue: stage slices 0 and 1; land 0; keep 1 in flight ----
    STAGE(1, 0, 0); STAGE(0, 0, 0);
    STAGE(1, 1, 1); STAGE(0, 1, 1);
    asm volatile("s_waitcnt vmcnt(4)" ::: "memory");
    __builtin_amdgcn_s_barrier();

    // ---- main loop: slices 0..125 (stage s+2 = 2..127) ----
    for (int j = 0; j < 63; ++j) {
        const int s = j * 2;
        SLICE_STEP(0, 1, s + 2, 1);
        SLICE_STEP(1, 1, s + 3, 1);
    }
    // ---- tail: slices 126, 127 ----
    SLICE_STEP(0, 0, 0, 2);   // s=126: vmcnt(0) lands slice 127
    SLICE_STEP(1, 0, 0, 3);   // s=127: bare

#undef SLICE_STEP
#undef STAGE

    // ---- epilogue: bias + scatter into q/k/v regions ----
    float* obase; int ldo; const float* bias; int cofs;
    if (col0 < NQ) {
        obase = out;                             ldo = NQ;  bias = bq; cofs = 0;
    } else if (col0 < NQ + NKV) {
        obase = out + (size_t)Mdim * NQ;         ldo = NKV; bias = bk; cofs = NQ;
    } else {
        obase = out + (size_t)Mdim * (NQ + NKV); ldo = NKV; bias = bv; cofs = NQ + NKV;
    }

    #pragma unroll
    for (int nf = 0; nf < 4; ++nf) {
        const int col = col0 + wc * 64 + nf * 16 + (lane & 15) - cofs;
        const float b = bias[col];
        #pragma unroll
        for (int mf = 0; mf < 8; ++mf) {
            #pragma unroll
            for (int r = 0; r < 4; ++r) {
                const int row = row0 + wr * 128 + mf * 16 + (lane >> 4) * 4 + r;
                obase[(size_t)row * ldo + col] = acc[mf][nf][r] + b;
            }
        }
    }
}

// ---------------------------------------------------------------------------
extern "C" void kernel_launch(void* const* d_in, const int* in_sizes, int n_in,
                              void* d_out, int out_size, void* d_ws, size_t ws_size,
                              hipStream_t stream) {
    const float* x  = (const float*)d_in[0];
    const float* Wq = (const float*)d_in[1];
    const float* Wk = (const float*)d_in[2];
    const float* Wv = (const float*)d_in[3];
    const float* bq = (const float*)d_in[4];
    const float* bk = (const float*)d_in[5];
    const float* bv = (const float*)d_in[6];
    const float* Aq = (const float*)d_in[7];
    const float* Bq = (const float*)d_in[8];
    const float* Ak = (const float*)d_in[9];
    const float* Bk = (const float*)d_in[10];
    const float* Av = (const float*)d_in[11];
    const float* Bv = (const float*)d_in[12];
    float* out = (float*)d_out;

    unsigned short* Xbf = (unsigned short*)d_ws;                   // 64 MB
    unsigned short* Wf  = Xbf + (size_t)Mdim * Kdim;               // 48 MB

    prep_kernel<<<WEFF_BLOCKS + CVT_BLOCKS, 256, 0, stream>>>(
        (const float4*)x, Xbf, Wq, Wk, Wv, Aq, Bq, Ak, Bk, Av, Bv, Wf);

    gemm_qkv_kernel<<<NWG, 512, 0, stream>>>(Xbf, Wf, bq, bk, bv, out);
}

// Round 11
// 437.628 us; speedup vs baseline: 9.1291x; 9.1291x over previous
//
#include <hip/hip_runtime.h>

// ---------------------------------------------------------------------------
// LoRA QKV fused projection on MI355X (gfx950)
// Weff-folding (LoRA into weights) + ONE bf16 MFMA GEMM.
// R11 = exact R4 revert (best measured: 397us GEMM / 461us total) + one
//       low-risk change: NONTEMPORAL epilogue stores. The 201MB write-once
//       fp32 output currently allocates in L2/LLC and evicts the X/Wf operand
//       panels (FETCH = 7x compulsory); NT stores stop the pollution.
// History: R5/R6/R9 (32x32 frags), R7 (reg pipelining), R8 (coarse phases),
// R10 (2 blocks/CU -> VGPR cap 64 -> scratch storm) ALL regressed vs R4.
// R4's schedule is the stable optimum of this template; registers (acc=128
// unified regs) + LDS both pin occupancy at 1 block/CU, closing that axis.
// ---------------------------------------------------------------------------

#define GLOBAL_AS __attribute__((address_space(1)))
#define LDS_AS    __attribute__((address_space(3)))

typedef __attribute__((ext_vector_type(8))) short  short8;   // 8 bf16 (MFMA A/B frag)
typedef __attribute__((ext_vector_type(4))) float  floatx4;  // MFMA C/D frag

constexpr int Mdim = 8192;   // B*S
constexpr int Kdim = 4096;   // H
constexpr int NQ   = 4096;
constexpr int NKV  = 1024;
constexpr int NTOT = NQ + 2 * NKV;  // 6144
constexpr float LORA_SCALE = 2.0f;

constexpr int BM = 256, BN = 256;
constexpr int TILES_M = Mdim / BM;      // 32
constexpr int TILES_N = NTOT / BN;      // 24
constexpr int NWG = TILES_M * TILES_N;  // 768 (%8==0 -> bijective XCD swizzle)
constexpr int NSLICE = Kdim / 32;       // 128 K-slices of 32

constexpr int WEFF_BLOCKS = (NTOT / 64) * (Kdim / 512);  // 768
constexpr int CVT_BLOCKS  = 2048;
constexpr int AT_STRIDE   = 516;

__device__ __forceinline__ unsigned short f2bf(float f) {
    union { float f; unsigned int u; } a; a.f = f;
    unsigned int r = a.u + 0x7FFFu + ((a.u >> 16) & 1u);
    return (unsigned short)(r >> 16);
}

// ---------------------------------------------------------------------------
// Fused prep (identical to R4):
//   blocks [0, WEFF_BLOCKS): Weff[n,h] = W[n,h] + 2*sum_r A[h,r]B[r,n] -> bf16
//   blocks [WEFF_BLOCKS, +CVT_BLOCKS): X fp32 -> bf16.
// ---------------------------------------------------------------------------
__global__ __launch_bounds__(256)
void prep_kernel(const float4* __restrict__ x4, unsigned short* __restrict__ Xbf,
                 const float* __restrict__ Wq, const float* __restrict__ Wk,
                 const float* __restrict__ Wv,
                 const float* __restrict__ Aq, const float* __restrict__ Bq,
                 const float* __restrict__ Ak, const float* __restrict__ Bk,
                 const float* __restrict__ Av, const float* __restrict__ Bv,
                 unsigned short* __restrict__ Wf) {
    __shared__ float AsT[16 * AT_STRIDE];   // ~33 KB: A^T chunk, [r][h_local]
    __shared__ float Bsc[64 * 16];          // 4 KB: 2*B[r, n0+..] as [n][r]

    const int tid = threadIdx.x;

    if (blockIdx.x >= WEFF_BLOCKS) {
        int i = (blockIdx.x - WEFF_BLOCKS) * 256 + tid;
        const int stride = CVT_BLOCKS * 256;
        const int n4 = Mdim * Kdim / 4;
        ushort4* out = (ushort4*)Xbf;
        for (; i < n4; i += stride) {
            float4 v = x4[i];
            ushort4 u;
            u.x = f2bf(v.x); u.y = f2bf(v.y); u.z = f2bf(v.z); u.w = f2bf(v.w);
            out[i] = u;
        }
        return;
    }

    const int n0 = (blockIdx.x >> 3) * 64;      // 64-row group (never straddles seg)
    const int h0 = (blockIdx.x & 7) * 512;

    const float* W; const float* A; const float* Bm; int O; int nn0;
    if (n0 < NQ)            { W = Wq; A = Aq; Bm = Bq; O = NQ;  nn0 = n0; }
    else if (n0 < NQ + NKV) { W = Wk; A = Ak; Bm = Bk; O = NKV; nn0 = n0 - NQ; }
    else                    { W = Wv; A = Av; Bm = Bv; O = NKV; nn0 = n0 - NQ - NKV; }

    {
        const float4* Af4 = (const float4*)(A) + h0 * 4;
        #pragma unroll
        for (int i = 0; i < 8; ++i) {
            const int f = i * 256 + tid;
            const float4 v = Af4[f];
            const int hl = f >> 2;
            const int r0 = (f & 3) * 4;
            AsT[(r0 + 0) * AT_STRIDE + hl] = v.x;
            AsT[(r0 + 1) * AT_STRIDE + hl] = v.y;
            AsT[(r0 + 2) * AT_STRIDE + hl] = v.z;
            AsT[(r0 + 3) * AT_STRIDE + hl] = v.w;
        }
    }
    {
        const int nl = tid & 63;
        const int rq = tid >> 6;        // 0..3
        #pragma unroll
        for (int j = 0; j < 4; ++j) {
            const int r = rq * 4 + j;
            Bsc[nl * 16 + r] = Bm[r * O + nn0 + nl] * LORA_SCALE;
        }
    }
    __syncthreads();

    const int wv_ = tid >> 6;
    const int lane = tid & 63;

    #pragma unroll
    for (int pass = 0; pass < 2; ++pass) {
        const int hl = pass * 256 + lane * 4;
        float4 areg[16];
        #pragma unroll
        for (int r = 0; r < 16; ++r)
            areg[r] = *(const float4*)(&AsT[r * AT_STRIDE + hl]);

        for (int i = 0; i < 16; ++i) {
            const int nl = wv_ * 16 + i;
            const float4 w4 = *(const float4*)(W + (size_t)(nn0 + nl) * Kdim + h0 + hl);
            const float4* b4 = (const float4*)(&Bsc[nl * 16]);
            float4 d = {0.f, 0.f, 0.f, 0.f};
            #pragma unroll
            for (int q = 0; q < 4; ++q) {
                const float4 b = b4[q];
                d.x += areg[q*4+0].x * b.x + areg[q*4+1].x * b.y + areg[q*4+2].x * b.z + areg[q*4+3].x * b.w;
                d.y += areg[q*4+0].y * b.x + areg[q*4+1].y * b.y + areg[q*4+2].y * b.z + areg[q*4+3].y * b.w;
                d.z += areg[q*4+0].z * b.x + areg[q*4+1].z * b.y + areg[q*4+2].z * b.z + areg[q*4+3].z * b.w;
                d.w += areg[q*4+0].w * b.x + areg[q*4+1].w * b.y + areg[q*4+2].w * b.z + areg[q*4+3].w * b.w;
            }
            ushort4 u;
            u.x = f2bf(w4.x + d.x); u.y = f2bf(w4.y + d.y);
            u.z = f2bf(w4.z + d.z); u.w = f2bf(w4.w + d.w);
            *(ushort4*)(Wf + (size_t)(n0 + nl) * Kdim + h0 + hl) = u;
        }
    }
}

// ---------------------------------------------------------------------------
// GEMM (R4 verbatim): out[M, NTOT] = Xbf[M,K] . Wf[NTOT,K]^T + bias.
// LDS: A/B rings of 4 K-slices (slice = 2 halves x 128 rows x 32 k, 16 KB).
// Schedule ledger (8 phases per 4 slices, main loop j=0..30):
//   ph0: g0+0/Mh0, stage A(g0+3)   ph4: g0+2/Mh0, stage A(g0+5)
//   ph1: g0+0/Mh1, stage B(g0+3)   ph5: g0+2/Mh1, stage B(g0+5)
//   ph2: g0+1/Mh0, stage A(g0+4)   ph6: g0+3/Mh0, stage A(g0+6)
//   ph3: g0+1/Mh1, stage B(g0+4)   ph7: g0+3/Mh1, stage B(g0+6)
//   vmcnt(4) end of ph3/ph7. Peeled last iter (g0=124): stage only slice 127
//   at ph0/ph1; vmcnt(4) end ph3 (lands 126), vmcnt(0) end ph5 (lands 127).
// Epilogue: bias + scatter, NONTEMPORAL stores (R11's only change).
// ---------------------------------------------------------------------------
__global__ __launch_bounds__(512, 2)
void gemm_qkv_kernel(const unsigned short* __restrict__ X,
                     const unsigned short* __restrict__ Wf,
                     const float* __restrict__ bq, const float* __restrict__ bk,
                     const float* __restrict__ bv,
                     float* __restrict__ out) {
    __shared__ __align__(16) unsigned short Abuf[4][8192];  // 64 KB
    __shared__ __align__(16) unsigned short Bbuf[4][8192];  // 64 KB

    const int tid  = threadIdx.x;
    const int lane = tid & 63;
    const int w    = tid >> 6;
    const int wr   = w >> 2;        // 0..1  (M half)
    const int wc   = w & 3;         // 0..3  (N quarter)

    int bid = blockIdx.x;
    bid = (bid & 7) * (NWG / 8) + (bid >> 3);   // XCD-aware, bijective (768%8==0)
    const int row0 = (bid / TILES_N) * BM;
    const int col0 = (bid % TILES_N) * BN;

    const int swz    = (((lane >> 4) ^ ((lane >> 1) & 3)) << 4);    // bytes
    const int aByte0 = (wr * 128 + (lane & 15)) * 64 + swz;
    const int bByte0 = (wc * 64  + (lane & 15)) * 64 + swz;

    const int srow = (w << 4) + (lane >> 2);                         // 0..127
    const int kswz = (((lane & 3) ^ ((lane >> 3) & 3)) << 3);        // elements
    const unsigned short* pA0 = X  + (size_t)(row0 + srow) * Kdim + kswz;
    const unsigned short* pA1 = pA0 + (size_t)128 * Kdim;
    const unsigned short* pB0 = Wf + (size_t)(col0 + srow) * Kdim + kswz;
    const unsigned short* pB1 = pB0 + (size_t)128 * Kdim;

    floatx4 acc[8][4];
    #pragma unroll
    for (int i = 0; i < 8; ++i)
        #pragma unroll
        for (int j = 0; j < 4; ++j)
            acc[i][j] = (floatx4){0.f, 0.f, 0.f, 0.f};

    short8 bf[4];

#define STAGE(MATA, SS)                                                          \
    { const int ss_ = (SS); const int st_ = (SS) & 3;                            \
      if (MATA) {                                                                \
        __builtin_amdgcn_global_load_lds((const GLOBAL_AS void*)(pA0 + ss_ * 32),\
            (LDS_AS void*)(&Abuf[st_][w * 512]),        16, 0, 0);               \
        __builtin_amdgcn_global_load_lds((const GLOBAL_AS void*)(pA1 + ss_ * 32),\
            (LDS_AS void*)(&Abuf[st_][4096 + w * 512]), 16, 0, 0);               \
      } else {                                                                   \
        __builtin_amdgcn_global_load_lds((const GLOBAL_AS void*)(pB0 + ss_ * 32),\
            (LDS_AS void*)(&Bbuf[st_][w * 512]),        16, 0, 0);               \
        __builtin_amdgcn_global_load_lds((const GLOBAL_AS void*)(pB1 + ss_ * 32),\
            (LDS_AS void*)(&Bbuf[st_][4096 + w * 512]), 16, 0, 0);               \
      } }

// WAITMODE: 0 = none, 1 = vmcnt(4), 2 = vmcnt(0)
#define DO_PHASE(G, MH, DOSTAGE, SMATA, SS, WAITMODE)                            \
    {                                                                            \
      const int slot_ = (G) & 3;                                                 \
      const char* abase_ = (const char*)Abuf + slot_ * 16384;                    \
      short8 af[4];                                                              \
      _Pragma("unroll")                                                          \
      for (int mf = 0; mf < 4; ++mf)                                             \
        af[mf] = *(const short8*)(abase_ + aByte0 + ((MH) * 4 + mf) * 1024);     \
      if ((MH) == 0) {                                                           \
        const char* bbase_ = (const char*)Bbuf + slot_ * 16384;                  \
        _Pragma("unroll")                                                        \
        for (int nf = 0; nf < 4; ++nf)                                           \
          bf[nf] = *(const short8*)(bbase_ + bByte0 + nf * 1024);                \
      }                                                                          \
      if (DOSTAGE) STAGE(SMATA, SS);                                             \
      __builtin_amdgcn_s_barrier();                                              \
      asm volatile("s_waitcnt lgkmcnt(0)");                                      \
      __builtin_amdgcn_s_setprio(1);                                             \
      _Pragma("unroll")                                                          \
      for (int mf = 0; mf < 4; ++mf)                                             \
        _Pragma("unroll")                                                        \
        for (int nf = 0; nf < 4; ++nf)                                           \
          acc[(MH) * 4 + mf][nf] = __builtin_amdgcn_mfma_f32_16x16x32_bf16(      \
              af[mf], bf[nf], acc[(MH) * 4 + mf][nf], 0, 0, 0);                  \
      __builtin_amdgcn_s_setprio(0);                                             \
      if ((WAITMODE) == 1) asm volatile("s_waitcnt vmcnt(4)" ::: "memory");      \
      if ((WAITMODE) == 2) asm volatile("s_waitcnt vmcnt(0)" ::: "memory");      \
      __builtin_amdgcn_s_barrier();                                              \
    }

    // ---- prologue: stage slices 0,1,2; land 0 and 1; keep 2 in flight ----
    STAGE(1, 0); STAGE(0, 0);
    STAGE(1, 1); STAGE(0, 1);
    STAGE(1, 2); STAGE(0, 2);
    asm volatile("s_waitcnt vmcnt(4)" ::: "memory");
    __builtin_amdgcn_s_barrier();

    for (int j = 0; j < NSLICE / 4 - 1; ++j) {
        const int g0 = j * 4;
        DO_PHASE(g0 + 0, 0, 1, 1, g0 + 3, 0);
        DO_PHASE(g0 + 0, 1, 1, 0, g0 + 3, 0);
        DO_PHASE(g0 + 1, 0, 1, 1, g0 + 4, 0);
        DO_PHASE(g0 + 1, 1, 1, 0, g0 + 4, 1);
        DO_PHASE(g0 + 2, 0, 1, 1, g0 + 5, 0);
        DO_PHASE(g0 + 2, 1, 1, 0, g0 + 5, 0);
        DO_PHASE(g0 + 3, 0, 1, 1, g0 + 6, 0);
        DO_PHASE(g0 + 3, 1, 1, 0, g0 + 6, 1);
    }
    // ---- peeled last iteration (g0 = 124): stage only slice 127 ----
    DO_PHASE(124, 0, 1, 1, 127, 0);
    DO_PHASE(124, 1, 1, 0, 127, 0);
    DO_PHASE(125, 0, 0, 0, 0,   0);
    DO_PHASE(125, 1, 0, 0, 0,   1);   // lands slice 126
    DO_PHASE(126, 0, 0, 0, 0,   0);
    DO_PHASE(126, 1, 0, 0, 0,   2);   // lands slice 127
    DO_PHASE(127, 0, 0, 0, 0,   0);
    DO_PHASE(127, 1, 0, 0, 0,   0);

#undef DO_PHASE
#undef STAGE

    // ---- epilogue: bias + scatter into q/k/v regions (nontemporal) ----
    float* obase; int ldo; const float* bias; int cofs;
    if (col0 < NQ) {
        obase = out;                             ldo = NQ;  bias = bq; cofs = 0;
    } else if (col0 < NQ + NKV) {
        obase = out + (size_t)Mdim * NQ;         ldo = NKV; bias = bk; cofs = NQ;
    } else {
        obase = out + (size_t)Mdim * (NQ + NKV); ldo = NKV; bias = bv; cofs = NQ + NKV;
    }

    #pragma unroll
    for (int nf = 0; nf < 4; ++nf) {
        const int col = col0 + wc * 64 + nf * 16 + (lane & 15) - cofs;
        const float b = bias[col];
        #pragma unroll
        for (int mf = 0; mf < 8; ++mf) {
            #pragma unroll
            for (int r = 0; r < 4; ++r) {
                const int row = row0 + wr * 128 + mf * 16 + (lane >> 4) * 4 + r;
                __builtin_nontemporal_store(acc[mf][nf][r] + b,
                                            &obase[(size_t)row * ldo + col]);
            }
        }
    }
}

// ---------------------------------------------------------------------------
extern "C" void kernel_launch(void* const* d_in, const int* in_sizes, int n_in,
                              void* d_out, int out_size, void* d_ws, size_t ws_size,
                              hipStream_t stream) {
    const float* x  = (const float*)d_in[0];
    const float* Wq = (const float*)d_in[1];
    const float* Wk = (const float*)d_in[2];
    const float* Wv = (const float*)d_in[3];
    const float* bq = (const float*)d_in[4];
    const float* bk = (const float*)d_in[5];
    const float* bv = (const float*)d_in[6];
    const float* Aq = (const float*)d_in[7];
    const float* Bq = (const float*)d_in[8];
    const float* Ak = (const float*)d_in[9];
    const float* Bk = (const float*)d_in[10];
    const float* Av = (const float*)d_in[11];
    const float* Bv = (const float*)d_in[12];
    float* out = (float*)d_out;

    unsigned short* Xbf = (unsigned short*)d_ws;                   // 64 MB
    unsigned short* Wf  = Xbf + (size_t)Mdim * Kdim;               // 48 MB

    prep_kernel<<<WEFF_BLOCKS + CVT_BLOCKS, 256, 0, stream>>>(
        (const float4*)x, Xbf, Wq, Wk, Wv, Aq, Bq, Ak, Bk, Av, Bv, Wf);

    gemm_qkv_kernel<<<NWG, 512, 0, stream>>>(Xbf, Wf, bq, bk, bv, out);
}